// Round 8
// baseline (138.221 us; speedup 1.0000x reference)
//
#include <hip/hip_runtime.h>

#define HH 512
#define WW 512
#define NB 32
#define EPSF 1e-7f
#define DTF 0.05f
#define RS1 2      // output rows per wave, pass 1  (256 strips/image)
#define RSF 2      // output rows per wave, pass 2  (256 strips/image)

// lane-to-lane pull via LDS pipe — used ONLY on computed (VALU) values, never
// on just-loaded data (bperm-after-load forces s_waitcnt vmcnt(0) per row and
// serializes all VMEM: that was R7's 57us latency wall).
__device__ __forceinline__ float bperm(int addr, float v) {
    return __int_as_float(__builtin_amdgcn_ds_bpermute(addr, __float_as_int(v)));
}

// One image row: 8 cols/lane (float4 x2) + 2 halo cols loaded DIRECTLY from
// global (strided dword, L1-served). All 4 loads are independent -> full MLP.
// v[1..8] = cols 8*lane..8*lane+7 ; v[0] = col-1 ; v[9] = col+8.
struct R10 { float v[10]; };

template<bool EDGE>
__device__ __forceinline__ void load_row10(const float* __restrict__ base, int row,
                                           int c4, int jl, int jr,
                                           bool lo, bool hi, R10& r) {
    int rc = row;
    if (EDGE) rc = min(max(row, 0), HH - 1);
    const float* __restrict__ rp = base + rc * WW;
    const float4* p = (const float4*)(rp + c4);
    float4 a = p[0], b = p[1];
    float l = rp[jl], h = rp[jr];
    if (EDGE && ((unsigned)row >= (unsigned)HH)) {
        a.x = a.y = a.z = a.w = 0.f;
        b.x = b.y = b.z = b.w = 0.f;
        l = 0.f; h = 0.f;
    }
    r.v[0] = lo ? 0.f : l;
    r.v[1] = a.x; r.v[2] = a.y; r.v[3] = a.z; r.v[4] = a.w;
    r.v[5] = b.x; r.v[6] = b.y; r.v[7] = b.z; r.v[8] = b.w;
    r.v[9] = hi ? 0.f : h;
}

// ---------------- Pass 1: partial max of e4 ----------------
template<bool EDGE>
__device__ __forceinline__ float e4_strip(const float* __restrict__ IM, int i0,
                                          int c4, int jl, int jr, bool lo, bool hi) {
    R10 A, B, C;
    load_row10<EDGE>(IM, i0 - 1, c4, jl, jr, lo, hi, A);
    load_row10<EDGE>(IM, i0,     c4, jl, jr, lo, hi, B);
    float m = 0.f;
    #pragma unroll
    for (int i = i0; i < i0 + RS1; ++i) {
        load_row10<EDGE>(IM, i + 1, c4, jl, jr, lo, hi, C);
        #pragma unroll
        for (int k = 1; k <= 8; ++k) {
            float ex = (A.v[k-1] - A.v[k+1]) + 2.f * (B.v[k-1] - B.v[k+1]) + (C.v[k-1] - C.v[k+1]);
            float ey = (A.v[k-1] - C.v[k-1]) + 2.f * (A.v[k] - C.v[k]) + (A.v[k+1] - C.v[k+1]);
            float s2 = ex * ex + ey * ey;
            m = fmaxf(m, s2 * s2);
        }
        A = B; B = C;
    }
    return m;
}

__global__ __launch_bounds__(256)
void max_e4_kernel(const float* __restrict__ img, float* __restrict__ partial) {
    const int wid  = blockIdx.x * 4 + (threadIdx.x >> 6);
    const int lane = threadIdx.x & 63;
    const int rs = wid & 255;                 // 256 strips of RS1 rows
    const int b  = wid >> 8;
    const int i0 = rs * RS1;
    const float* __restrict__ IM = img + (size_t)b * (HH * WW);
    const bool lo = (lane == 0), hi = (lane == 63);
    const int c4 = 8 * lane;
    const int jl = max(c4 - 1, 0), jr = min(c4 + 8, WW - 1);

    float m = (rs == 0 || rs == 255)
        ? e4_strip<true >(IM, i0, c4, jl, jr, lo, hi)
        : e4_strip<false>(IM, i0, c4, jl, jr, lo, hi);

    for (int off = 32; off > 0; off >>= 1)
        m = fmaxf(m, __shfl_down(m, off, 64));
    if (lane == 0) partial[wid] = m;          // 8192 partials, all written
}

// ---------------- Pass 1b: 8192 partials -> M ----------------
__global__ __launch_bounds__(256)
void reduce_max(const float* __restrict__ partial, float* __restrict__ wsmax) {
    const float4* p4 = (const float4*)partial;      // 2048 float4s
    float v = 0.f;
    #pragma unroll
    for (int k = 0; k < 8; ++k) {
        float4 a = p4[threadIdx.x + 256 * k];
        v = fmaxf(v, fmaxf(fmaxf(a.x, a.y), fmaxf(a.z, a.w)));
    }
    for (int off = 32; off > 0; off >>= 1)
        v = fmaxf(v, __shfl_down(v, off, 64));
    __shared__ float smax[4];
    const int lane = threadIdx.x & 63, w = threadIdx.x >> 6;
    if (lane == 0) smax[w] = v;
    __syncthreads();
    if (threadIdx.x == 0)
        wsmax[0] = fmaxf(fmaxf(smax[0], smax[1]), fmaxf(smax[2], smax[3]));
}

// ---------------- Pass 2: wave-per-row-strip fused forcing function ----------------
template<bool EDGE>
__device__ __forceinline__ void ff_impl(const float* __restrict__ U,
                                        const float* __restrict__ IM,
                                        float* __restrict__ O,
                                        int o0, int c4, int jl, int jr,
                                        int bpu, int bpd,
                                        bool lo, bool hi, float M,
                                        float dta, float dtb, float dtg) {
    // rolling state: img rows o,o+1 ; u rows o-1..o+1 ; e/px/py history
    R10 I0, I1, R1, R2, E2 = {}, PX2 = {};
    float R0[9] = {}, E1[9] = {}, PY1[9] = {}, PY2[9] = {};

    load_row10<EDGE>(IM, o0 - 2, c4, jl, jr, lo, hi, I0);
    load_row10<EDGE>(IM, o0 - 1, c4, jl, jr, lo, hi, I1);
    load_row10<EDGE>(U,  o0 - 2, c4, jl, jr, lo, hi, R1);
    load_row10<EDGE>(U,  o0 - 1, c4, jl, jr, lo, hi, R2);

    #pragma unroll
    for (int o = o0 - 2; o < o0 + RSF; ++o) {
        R10 C, W;
        load_row10<EDGE>(IM, o + 2, c4, jl, jr, lo, hi, C);
        load_row10<EDGE>(U,  o + 2, c4, jl, jr, lo, hi, W);

        // e / px / py at row o+1 (img rows o..o+2 ; u rows o..o+2)
        R10 eN, PXN;
        float PYN[9];
        const bool zrow = EDGE && (o < -1 || o >= HH - 1);   // row o+1 outside plane
        #pragma unroll
        for (int k = 1; k <= 8; ++k) {
            float ex = (I0.v[k-1] - I0.v[k+1]) + 2.f * (I1.v[k-1] - I1.v[k+1]) + (C.v[k-1] - C.v[k+1]);
            float ey = (I0.v[k-1] - C.v[k-1]) + 2.f * (I0.v[k] - C.v[k]) + (I0.v[k+1] - C.v[k+1]);
            float s2 = ex * ex + ey * ey;
            float e  = M * __builtin_amdgcn_rcpf(s2 * s2 + M);
            float gux = R2.v[k+1] - R2.v[k-1];
            float guy = R1.v[k] - W.v[k];
            float rn  = __builtin_amdgcn_rsqf(gux * gux + guy * guy + EPSF);
            eN.v[k]  = zrow ? 0.f : e;
            PXN.v[k] = zrow ? 0.f : gux * rn;
            PYN[k]   = zrow ? 0.f : guy * rn;
        }
        {   // halos for eN / PXN — computed values, bperm is VALU->LDS only
            float a = bperm(bpu, eN.v[8]),  bb = bperm(bpd, eN.v[1]);
            float c = bperm(bpu, PXN.v[8]), d  = bperm(bpd, PXN.v[1]);
            eN.v[0]  = lo ? 0.f : a;  eN.v[9]  = hi ? 0.f : bb;
            PXN.v[0] = lo ? 0.f : c;  PXN.v[9] = hi ? 0.f : d;
        }

        if (o >= o0) {   // emit output row o
            float vals[8];
            #pragma unroll
            for (int k = 1; k <= 8; ++k) {
                float gex = E2.v[k+1] - E2.v[k-1];
                float gey = E1[k] - eN.v[k];
                float xp = R1.v[k+1] - R1.v[k], xn = R1.v[k] - R1.v[k-1];
                float yp = R0[k] - R1.v[k],     yn = R1.v[k] - R2.v[k];
                float tr = fmaxf(gex, 0.f) * xp + fminf(gex, 0.f) * xn
                         + fmaxf(gey, 0.f) * yp + fminf(gey, 0.f) * yn;
                float gxc = R1.v[k+1] - R1.v[k-1], gyc = R0[k] - R2.v[k];
                float ncv = __builtin_amdgcn_sqrtf(gxc * gxc + gyc * gyc + EPSF);
                float kap = (PX2.v[k+1] - PX2.v[k-1]) + (PY1[k] - PYN[k]);
                vals[k-1] = R1.v[k] + E2.v[k] * ncv * (kap * dta + dtg) + tr * dtb;
            }
            float4* p = (float4*)(O + o * WW + c4);
            p[0] = make_float4(vals[0], vals[1], vals[2], vals[3]);
            p[1] = make_float4(vals[4], vals[5], vals[6], vals[7]);
        }

        // roll (pure SSA renames after full unroll)
        I0 = I1; I1 = C;
        #pragma unroll
        for (int k = 1; k <= 8; ++k) { R0[k] = R1.v[k]; E1[k] = E2.v[k]; PY1[k] = PY2[k]; PY2[k] = PYN[k]; }
        R1 = R2; R2 = W;
        E2 = eN; PX2 = PXN;
    }
}

__global__ __launch_bounds__(256)
void fused_ff(const float* __restrict__ u, const float* __restrict__ img,
              const float* __restrict__ pa, const float* __restrict__ pb,
              const float* __restrict__ pg, const float* __restrict__ wsmax,
              float* __restrict__ out) {
    const int wid  = blockIdx.x * 4 + (threadIdx.x >> 6);
    const int lane = threadIdx.x & 63;
    const int rs = wid & 255;                 // 256 strips of RSF rows
    const int b  = wid >> 8;
    const int o0 = rs * RSF;
    const size_t base = (size_t)b * (HH * WW);
    const bool lo = (lane == 0), hi = (lane == 63);
    const int c4 = 8 * lane;
    const int jl = max(c4 - 1, 0), jr = min(c4 + 8, WW - 1);
    const int bpu = ((lane + 63) & 63) << 2, bpd = ((lane + 1) & 63) << 2;

    const float M   = wsmax[0];
    const float dta = DTF * pa[0];
    const float dtb = 20.f * DTF * pb[0];
    const float dtg = DTF * pg[0];

    // interior strips (rs 1..254): rows o0-2 .. o0+3 all inside [0,511] -> no row logic
    if (rs == 0 || rs == 255)
        ff_impl<true >(u + base, img + base, out + base, o0, c4, jl, jr, bpu, bpd, lo, hi, M, dta, dtb, dtg);
    else
        ff_impl<false>(u + base, img + base, out + base, o0, c4, jl, jr, bpu, bpd, lo, hi, M, dta, dtb, dtg);
}

extern "C" void kernel_launch(void* const* d_in, const int* in_sizes, int n_in,
                              void* d_out, int out_size, void* d_ws, size_t ws_size,
                              hipStream_t stream) {
    const float* u   = (const float*)d_in[0];
    const float* img = (const float*)d_in[1];
    const float* pa  = (const float*)d_in[2];
    const float* pb  = (const float*)d_in[3];
    const float* pg  = (const float*)d_in[4];
    float* out = (float*)d_out;
    float* partial = (float*)d_ws;        // 8192 floats, all written unconditionally
    float* wsmax   = partial + 8192;

    // pass 1: 256 strips x 32 images = 8192 waves = 2048 blocks (8/CU)
    max_e4_kernel<<<2048, 256, 0, stream>>>(img, partial);
    reduce_max<<<1, 256, 0, stream>>>(partial, wsmax);
    // pass 2: 256 strips x 32 images = 8192 waves = 2048 blocks (8/CU)
    fused_ff<<<2048, 256, 0, stream>>>(u, img, pa, pb, pg, wsmax, out);
}

// Round 9
// 128.916 us; speedup vs baseline: 1.0722x; 1.0722x over previous
//
#include <hip/hip_runtime.h>

#define HH 512
#define WW 512
#define NB 32
#define EPSF 1e-7f
#define DTF 0.05f
#define RS1 4      // output rows per wave, pass 1  (128 strips/image)
#define RSF 2      // output rows per wave, pass 2  (256 strips/image)

// lane-to-lane pull via LDS pipe. Safe here: used once per wave AFTER the
// single bulk-load drain (R7's mistake was a bperm->vmcnt(0) per row).
__device__ __forceinline__ float bperm(int addr, float v) {
    return __int_as_float(__builtin_amdgcn_ds_bpermute(addr, __float_as_int(v)));
}

// v[1..8] = cols 8*lane..8*lane+7 ; v[0]/v[9] = halo cols from neighbor lanes.
struct R10 { float v[10]; };
struct F8  { float v[8]; };   // raw loaded row, pre-halo

// Phase-1 load: float4 x2, NO consumption. EDGE: row clamped (load always
// valid) and zeroed after if logically outside the plane.
template<bool EDGE>
__device__ __forceinline__ void load_row8(const float* __restrict__ base, int row,
                                          int c4, F8& r) {
    int rc = row;
    if (EDGE) rc = min(max(row, 0), HH - 1);
    const float4* p = (const float4*)(base + rc * WW + c4);
    float4 a = p[0], b = p[1];
    if (EDGE && ((unsigned)row >= (unsigned)HH)) {
        a.x = a.y = a.z = a.w = 0.f;
        b.x = b.y = b.z = b.w = 0.f;
    }
    r.v[0] = a.x; r.v[1] = a.y; r.v[2] = a.z; r.v[3] = a.w;
    r.v[4] = b.x; r.v[5] = b.y; r.v[6] = b.z; r.v[7] = b.w;
}

// Phase-2 halo expansion via bperm (runs after the single bulk drain).
__device__ __forceinline__ void expand(const F8& s, int bpu, int bpd,
                                       bool lo, bool hi, R10& r) {
    #pragma unroll
    for (int k = 0; k < 8; ++k) r.v[k + 1] = s.v[k];
    float l = bperm(bpu, s.v[7]);
    float h = bperm(bpd, s.v[0]);
    r.v[0] = lo ? 0.f : l;
    r.v[9] = hi ? 0.f : h;
}

// ---------------- Pass 1: partial max of e4 (load-all-then-compute) ----------------
template<bool EDGE>
__device__ __forceinline__ float e4_strip(const float* __restrict__ IM, int i0,
                                          int c4, int bpu, int bpd, bool lo, bool hi) {
    F8 raw[RS1 + 2];
    #pragma unroll
    for (int s = 0; s < RS1 + 2; ++s)              // ALL loads first: MLP = RS1+2 x2
        load_row8<EDGE>(IM, i0 - 1 + s, c4, raw[s]);
    R10 I[RS1 + 2];
    #pragma unroll
    for (int s = 0; s < RS1 + 2; ++s)              // one drain, then bperms
        expand(raw[s], bpu, bpd, lo, hi, I[s]);
    float m = 0.f;
    #pragma unroll
    for (int t = 0; t < RS1; ++t) {
        #pragma unroll
        for (int k = 1; k <= 8; ++k) {
            float ex = (I[t].v[k-1] - I[t].v[k+1]) + 2.f * (I[t+1].v[k-1] - I[t+1].v[k+1])
                     + (I[t+2].v[k-1] - I[t+2].v[k+1]);
            float ey = (I[t].v[k-1] - I[t+2].v[k-1]) + 2.f * (I[t].v[k] - I[t+2].v[k])
                     + (I[t].v[k+1] - I[t+2].v[k+1]);
            float s2 = ex * ex + ey * ey;
            m = fmaxf(m, s2 * s2);
        }
    }
    return m;
}

__global__ __launch_bounds__(256)
void max_e4_kernel(const float* __restrict__ img, float* __restrict__ partial) {
    const int wid  = blockIdx.x * 4 + (threadIdx.x >> 6);
    const int lane = threadIdx.x & 63;
    const int rs = wid & 127;                 // 128 strips of RS1 rows
    const int b  = wid >> 7;
    const int i0 = rs * RS1;
    const float* __restrict__ IM = img + (size_t)b * (HH * WW);
    const bool lo = (lane == 0), hi = (lane == 63);
    const int c4 = 8 * lane;
    const int bpu = ((lane + 63) & 63) << 2, bpd = ((lane + 1) & 63) << 2;

    float m = (rs == 0 || rs == 127)
        ? e4_strip<true >(IM, i0, c4, bpu, bpd, lo, hi)
        : e4_strip<false>(IM, i0, c4, bpu, bpd, lo, hi);

    for (int off = 32; off > 0; off >>= 1)
        m = fmaxf(m, __shfl_down(m, off, 64));
    if (lane == 0) partial[wid] = m;          // 4096 partials, all written
}

// ---------------- Pass 1b: 4096 partials -> M ----------------
__global__ __launch_bounds__(256)
void reduce_max(const float* __restrict__ partial, float* __restrict__ wsmax) {
    const float4* p4 = (const float4*)partial;      // 1024 float4s
    float v = 0.f;
    #pragma unroll
    for (int k = 0; k < 4; ++k) {
        float4 a = p4[threadIdx.x + 256 * k];
        v = fmaxf(v, fmaxf(fmaxf(a.x, a.y), fmaxf(a.z, a.w)));
    }
    for (int off = 32; off > 0; off >>= 1)
        v = fmaxf(v, __shfl_down(v, off, 64));
    __shared__ float smax[4];
    const int lane = threadIdx.x & 63, w = threadIdx.x >> 6;
    if (lane == 0) smax[w] = v;
    __syncthreads();
    if (threadIdx.x == 0)
        wsmax[0] = fmaxf(fmaxf(smax[0], smax[1]), fmaxf(smax[2], smax[3]));
}

// ---------------- Pass 2: load-all-then-compute fused forcing function ----------------
// Wave owns 2 output rows x 512 cols. 24 float4 loads issued back-to-back,
// ONE vmcnt drain, then pure register/DS compute.
template<bool EDGE>
__device__ __forceinline__ void ff_impl(const float* __restrict__ U,
                                        const float* __restrict__ IM,
                                        float* __restrict__ O,
                                        int o0, int c4, int bpu, int bpd,
                                        bool lo, bool hi, float M,
                                        float dta, float dtb, float dtg) {
    // ---- phase 1: ALL loads (12 rows x 2 float4, no consumers in between)
    F8 imr[6], uur[6];
    #pragma unroll
    for (int s = 0; s < 6; ++s) load_row8<EDGE>(IM, o0 - 2 + s, c4, imr[s]);
    #pragma unroll
    for (int s = 0; s < 6; ++s) load_row8<EDGE>(U,  o0 - 2 + s, c4, uur[s]);

    // ---- phase 2: halo expansion (single implicit vmcnt drain here)
    R10 I[6], Uu[6];
    #pragma unroll
    for (int s = 0; s < 6; ++s) expand(imr[s], bpu, bpd, lo, hi, I[s]);
    #pragma unroll
    for (int s = 0; s < 6; ++s) expand(uur[s], bpu, bpd, lo, hi, Uu[s]);

    // ---- phase 3: E (4 rows), PX (rows 1,2 only), PY (4 rows)
    // E[rr]/PY[rr] at image row o0-1+rr, from I/Uu[rr..rr+2].
    R10 E[4], PX[2];
    float PY[4][8];
    #pragma unroll
    for (int rr = 0; rr < 4; ++rr) {
        const bool zrow = EDGE && ((unsigned)(o0 - 1 + rr) >= (unsigned)HH);
        #pragma unroll
        for (int k = 1; k <= 8; ++k) {
            float ex = (I[rr].v[k-1] - I[rr].v[k+1]) + 2.f * (I[rr+1].v[k-1] - I[rr+1].v[k+1])
                     + (I[rr+2].v[k-1] - I[rr+2].v[k+1]);
            float ey = (I[rr].v[k-1] - I[rr+2].v[k-1]) + 2.f * (I[rr].v[k] - I[rr+2].v[k])
                     + (I[rr].v[k+1] - I[rr+2].v[k+1]);
            float s2 = ex * ex + ey * ey;
            float e  = M * __builtin_amdgcn_rcpf(s2 * s2 + M);
            float gux = Uu[rr+1].v[k+1] - Uu[rr+1].v[k-1];
            float guy = Uu[rr].v[k] - Uu[rr+2].v[k];
            float rn  = __builtin_amdgcn_rsqf(gux * gux + guy * guy + EPSF);
            E[rr].v[k]  = zrow ? 0.f : e;
            PY[rr][k-1] = zrow ? 0.f : guy * rn;
            if (rr == 1 || rr == 2)
                PX[rr-1].v[k] = zrow ? 0.f : gux * rn;
        }
    }
    // halos only where consumed horizontally: E rows 1,2 (gex), PX rows 1,2 (kappa)
    #pragma unroll
    for (int rr = 1; rr <= 2; ++rr) {
        float a = bperm(bpu, E[rr].v[8]),      bb = bperm(bpd, E[rr].v[1]);
        float c = bperm(bpu, PX[rr-1].v[8]),   d  = bperm(bpd, PX[rr-1].v[1]);
        E[rr].v[0]    = lo ? 0.f : a;  E[rr].v[9]    = hi ? 0.f : bb;
        PX[rr-1].v[0] = lo ? 0.f : c;  PX[rr-1].v[9] = hi ? 0.f : d;
    }

    // ---- phase 4: outputs, rows o0 and o0+1
    #pragma unroll
    for (int oo = 0; oo < 2; ++oo) {
        float vals[8];
        #pragma unroll
        for (int k = 1; k <= 8; ++k) {
            float gex = E[oo+1].v[k+1] - E[oo+1].v[k-1];
            float gey = E[oo].v[k] - E[oo+2].v[k];
            float uc = Uu[oo+2].v[k];
            float xp = Uu[oo+2].v[k+1] - uc, xn = uc - Uu[oo+2].v[k-1];
            float yp = Uu[oo+1].v[k] - uc,   yn = uc - Uu[oo+3].v[k];
            float tr = fmaxf(gex, 0.f) * xp + fminf(gex, 0.f) * xn
                     + fmaxf(gey, 0.f) * yp + fminf(gey, 0.f) * yn;
            float gxc = Uu[oo+2].v[k+1] - Uu[oo+2].v[k-1];
            float gyc = Uu[oo+1].v[k] - Uu[oo+3].v[k];
            float ncv = __builtin_amdgcn_sqrtf(gxc * gxc + gyc * gyc + EPSF);
            float kap = (PX[oo].v[k+1] - PX[oo].v[k-1]) + (PY[oo][k-1] - PY[oo+2][k-1]);
            vals[k-1] = uc + E[oo+1].v[k] * ncv * (kap * dta + dtg) + tr * dtb;
        }
        float4* p = (float4*)(O + (o0 + oo) * WW + c4);
        p[0] = make_float4(vals[0], vals[1], vals[2], vals[3]);
        p[1] = make_float4(vals[4], vals[5], vals[6], vals[7]);
    }
}

__global__ __launch_bounds__(256)
void fused_ff(const float* __restrict__ u, const float* __restrict__ img,
              const float* __restrict__ pa, const float* __restrict__ pb,
              const float* __restrict__ pg, const float* __restrict__ wsmax,
              float* __restrict__ out) {
    const int wid  = blockIdx.x * 4 + (threadIdx.x >> 6);
    const int lane = threadIdx.x & 63;
    const int rs = wid & 255;                 // 256 strips of RSF rows
    const int b  = wid >> 8;
    const int o0 = rs * RSF;
    const size_t base = (size_t)b * (HH * WW);
    const bool lo = (lane == 0), hi = (lane == 63);
    const int c4 = 8 * lane;
    const int bpu = ((lane + 63) & 63) << 2, bpd = ((lane + 1) & 63) << 2;

    const float M   = wsmax[0];
    const float dta = DTF * pa[0];
    const float dtb = 20.f * DTF * pb[0];
    const float dtg = DTF * pg[0];

    // interior strips (rs 1..254): rows o0-2 .. o0+3 all inside [0,511]
    if (rs == 0 || rs == 255)
        ff_impl<true >(u + base, img + base, out + base, o0, c4, bpu, bpd, lo, hi, M, dta, dtb, dtg);
    else
        ff_impl<false>(u + base, img + base, out + base, o0, c4, bpu, bpd, lo, hi, M, dta, dtb, dtg);
}

extern "C" void kernel_launch(void* const* d_in, const int* in_sizes, int n_in,
                              void* d_out, int out_size, void* d_ws, size_t ws_size,
                              hipStream_t stream) {
    const float* u   = (const float*)d_in[0];
    const float* img = (const float*)d_in[1];
    const float* pa  = (const float*)d_in[2];
    const float* pb  = (const float*)d_in[3];
    const float* pg  = (const float*)d_in[4];
    float* out = (float*)d_out;
    float* partial = (float*)d_ws;        // 4096 floats, all written unconditionally
    float* wsmax   = partial + 4096;

    // pass 1: 128 strips x 32 images = 4096 waves = 1024 blocks
    max_e4_kernel<<<1024, 256, 0, stream>>>(img, partial);
    reduce_max<<<1, 256, 0, stream>>>(partial, wsmax);
    // pass 2: 256 strips x 32 images = 8192 waves = 2048 blocks
    fused_ff<<<2048, 256, 0, stream>>>(u, img, pa, pb, pg, wsmax, out);
}